// Round 8
// baseline (4166.658 us; speedup 1.0000x reference)
//
#include <hip/hip_runtime.h>
#include <hip/hip_bf16.h>
#include <stdint.h>

// ---------------------------------------------------------------------------
// S4 / Conformer-style encoder, 6 layers. B=8 T=2048 D=512 F=2048 N=64 K=31
// R8: GEMM register blocking up (4 waves, per-wave 128x128 -> 1.5x fewer LDS
// bytes/FLOP; LDS-read-BW model fit from R4-R7 nulls); R5-proven 2-phase
// sync; chunked XCD swizzle (R7, FETCH-verified). GLU fused into bneck GEMM
// epilogue via interleaved weights + shfl_xor(1).
// ---------------------------------------------------------------------------

#define NL 6
#define TT 2048
#define BB 8
#define DD 512
#define FF 2048
#define ROWS (BB*TT)          // 16384

typedef __attribute__((ext_vector_type(4))) float f32x4;
typedef __attribute__((ext_vector_type(8))) short s16x8;

#define DEVI __device__ __forceinline__

DEVI float bf2f(uint32_t u) { union { uint32_t i; float f; } v; v.i = u << 16; return v.f; }
DEVI uint16_t f2bf(float f) {
    union { float f; uint32_t i; } v; v.f = f;
    uint32_t x = v.i;
    return (uint16_t)((x + 0x7fffu + ((x >> 16) & 1u)) >> 16);   // RNE
}
// tanh-approx gelu == x * sigmoid(1.59577x + 0.0713548x^3)
DEVI float gelu_f(float x) {
    float x2 = x * x;
    float z  = x * fmaf(x2, 0.07135481627f, 1.5957691216f);
    return x * __builtin_amdgcn_rcpf(1.0f + __expf(-z));
}
DEVI float sigm(float x) { return __builtin_amdgcn_rcpf(1.0f + __expf(-x)); }

// async global->LDS, 16B/lane; dest = wave-uniform base, HW adds lane*16
DEVI void gload16(const uint16_t* g, uint16_t* l) {
    __builtin_amdgcn_global_load_lds((const __attribute__((address_space(1))) void*)g,
                                     (__attribute__((address_space(3))) void*)l, 16, 0, 0);
}

// ---------------- weight prep ----------------------------------------------
__global__ void k_wtrans(const float* __restrict__ src, uint16_t* __restrict__ dst,
                         int K, int N) {
    __shared__ float tile[32][33];
    int l = blockIdx.z;
    const float* s = src + (size_t)l * K * N;
    uint16_t*    d = dst + (size_t)l * N * K;
    int n0 = blockIdx.x * 32, k0 = blockIdx.y * 32;
    int tx = threadIdx.x, ty = threadIdx.y;
#pragma unroll
    for (int i = 0; i < 4; i++) {
        int k = k0 + ty + i * 8;
        tile[ty + i * 8][tx] = s[(size_t)k * N + n0 + tx];
    }
    __syncthreads();
#pragma unroll
    for (int i = 0; i < 4; i++) {
        int n = n0 + ty + i * 8;
        d[(size_t)n * K + k0 + tx] = f2bf(tile[tx][ty + i * 8]);
    }
}
__global__ void k_wcvt(const float* __restrict__ src, uint16_t* __restrict__ dst, int n) {
    int i = blockIdx.x * 256 + threadIdx.x;
    if (i < n) dst[i] = f2bf(src[i]);
}
// bneck_w [L][1024][512] -> interleaved bf16: row 2m = a-row m, 2m+1 = g-row 512+m.
// bneck_b [L][1024] -> interleaved f32 bias likewise.
__global__ void k_wglu(const float* __restrict__ w, const float* __restrict__ b,
                       uint16_t* __restrict__ wd, float* __restrict__ bd) {
    int i = blockIdx.x * 256 + threadIdx.x;
    int tot = NL * 1024 * DD;
    if (i < tot) {
        int l = i / (1024 * DD), r = (i / DD) % 1024, k = i % DD;
        int srow = (r & 1) ? (512 + (r >> 1)) : (r >> 1);
        wd[i] = f2bf(w[((size_t)l * 1024 + srow) * DD + k]);
    }
    if (i < NL * 1024) {
        int l = i >> 10, r = i & 1023;
        int srow = (r & 1) ? (512 + (r >> 1)) : (r >> 1);
        bd[i] = b[l * 1024 + srow];
    }
}
__global__ void k_dwt(const float* __restrict__ dw, float* __restrict__ dwt) {
    int i = blockIdx.x * 256 + threadIdx.x;
    int tot = NL * DD * 31;
    if (i >= tot) return;
    int l = i / (DD * 31), r = i % (DD * 31), d = r / 31, k = r % 31;
    dwt[(size_t)l * 31 * DD + k * DD + d] = dw[i];
}
// src [16384][80] f32 -> [16384][128] bf16 (zero-pad K)
__global__ void k_srcpad(const float* __restrict__ src, uint16_t* __restrict__ dst) {
    int i = blockIdx.x * 256 + threadIdx.x;
    if (i >= ROWS * 128) return;
    int r = i >> 7, c = i & 127;
    dst[i] = (c < 80) ? f2bf(src[(size_t)r * 80 + c]) : (uint16_t)0;
}
// src_w [80][512] f32 -> [512][128] bf16 transposed+padded
__global__ void k_wsrcpad(const float* __restrict__ w, uint16_t* __restrict__ dst) {
    int i = blockIdx.x * 256 + threadIdx.x;
    if (i >= DD * 128) return;
    int n = i >> 7, k = i & 127;
    dst[i] = (k < 80) ? f2bf(w[(size_t)k * DD + n]) : (uint16_t)0;
}

// ---------------- LayerNorm (wave per row) ----------------------------------
template <int MODE>
__global__ void k_ln(const float* __restrict__ in, void* __restrict__ outp,
                     const float* __restrict__ gam, const float* __restrict__ bet,
                     const float* __restrict__ spk, float eps) {
    int row  = blockIdx.x * 4 + (threadIdx.x >> 6);
    int lane = threadIdx.x & 63;
    const float* x = in + (size_t)row * DD;
    float4 a0 = *(const float4*)&x[lane * 4];
    float4 a1 = *(const float4*)&x[256 + lane * 4];
    float v[8] = {a0.x, a0.y, a0.z, a0.w, a1.x, a1.y, a1.z, a1.w};
    float s = 0.f, q = 0.f;
#pragma unroll
    for (int i = 0; i < 8; i++) { s += v[i]; q += v[i] * v[i]; }
#pragma unroll
    for (int m = 1; m < 64; m <<= 1) { s += __shfl_xor(s, m); q += __shfl_xor(q, m); }
    float mean = s * (1.0f / 512.0f);
    float var  = fmaxf(q * (1.0f / 512.0f) - mean * mean, 0.0f);
    float inv  = rsqrtf(var + eps);
    float4 g0 = *(const float4*)&gam[lane * 4];
    float4 g1 = *(const float4*)&gam[256 + lane * 4];
    float4 b0 = *(const float4*)&bet[lane * 4];
    float4 b1 = *(const float4*)&bet[256 + lane * 4];
    float gv[8] = {g0.x, g0.y, g0.z, g0.w, g1.x, g1.y, g1.z, g1.w};
    float bv[8] = {b0.x, b0.y, b0.z, b0.w, b1.x, b1.y, b1.z, b1.w};
    float y[8];
#pragma unroll
    for (int i = 0; i < 8; i++) y[i] = (v[i] - mean) * inv * gv[i] + bv[i];
    uint16_t* o = (uint16_t*)outp + (size_t)row * DD;
    uint2 p0, p1;
    p0.x = (uint32_t)f2bf(y[0]) | ((uint32_t)f2bf(y[1]) << 16);
    p0.y = (uint32_t)f2bf(y[2]) | ((uint32_t)f2bf(y[3]) << 16);
    p1.x = (uint32_t)f2bf(y[4]) | ((uint32_t)f2bf(y[5]) << 16);
    p1.y = (uint32_t)f2bf(y[6]) | ((uint32_t)f2bf(y[7]) << 16);
    *(uint2*)&o[lane * 4]       = p0;
    *(uint2*)&o[256 + lane * 4] = p1;
}

// ---------------- double-LN -------------------------------------------------
template <int M2>
__global__ void k_ln2(const float* __restrict__ in, float* __restrict__ X,
                      void* __restrict__ out2,
                      const float* __restrict__ g1, const float* __restrict__ b1,
                      const float* __restrict__ g2, const float* __restrict__ b2,
                      const float* __restrict__ spk, float eps2) {
    int row  = blockIdx.x * 4 + (threadIdx.x >> 6);
    int lane = threadIdx.x & 63;
    const float* x = in + (size_t)row * DD;
    float4 a0 = *(const float4*)&x[lane * 4];
    float4 a1 = *(const float4*)&x[256 + lane * 4];
    float v[8] = {a0.x, a0.y, a0.z, a0.w, a1.x, a1.y, a1.z, a1.w};
    float s = 0.f, q = 0.f;
#pragma unroll
    for (int i = 0; i < 8; i++) { s += v[i]; q += v[i] * v[i]; }
#pragma unroll
    for (int m = 1; m < 64; m <<= 1) { s += __shfl_xor(s, m); q += __shfl_xor(q, m); }
    float mean = s * (1.0f / 512.0f);
    float var  = fmaxf(q * (1.0f / 512.0f) - mean * mean, 0.0f);
    float inv  = rsqrtf(var + 1e-5f);
    float4 g0 = *(const float4*)&g1[lane * 4];
    float4 g1v = *(const float4*)&g1[256 + lane * 4];
    float4 b0 = *(const float4*)&b1[lane * 4];
    float4 b1v = *(const float4*)&b1[256 + lane * 4];
    float gv[8] = {g0.x, g0.y, g0.z, g0.w, g1v.x, g1v.y, g1v.z, g1v.w};
    float bv[8] = {b0.x, b0.y, b0.z, b0.w, b1v.x, b1v.y, b1v.z, b1v.w};
    float y[8];
    float s2 = 0.f, q2 = 0.f;
#pragma unroll
    for (int i = 0; i < 8; i++) {
        y[i] = (v[i] - mean) * inv * gv[i] + bv[i];
        s2 += y[i]; q2 += y[i] * y[i];
    }
    if (M2 == 6) {
        float* xo = X + (size_t)row * DD;
        *(float4*)&xo[lane * 4]       = make_float4(y[0], y[1], y[2], y[3]);
        *(float4*)&xo[256 + lane * 4] = make_float4(y[4], y[5], y[6], y[7]);
    }
#pragma unroll
    for (int m = 1; m < 64; m <<= 1) { s2 += __shfl_xor(s2, m); q2 += __shfl_xor(q2, m); }
    float mean2 = s2 * (1.0f / 512.0f);
    float var2  = fmaxf(q2 * (1.0f / 512.0f) - mean2 * mean2, 0.0f);
    float inv2  = rsqrtf(var2 + eps2);
    float4 G0 = *(const float4*)&g2[lane * 4];
    float4 G1 = *(const float4*)&g2[256 + lane * 4];
    float4 B0 = *(const float4*)&b2[lane * 4];
    float4 B1v = *(const float4*)&b2[256 + lane * 4];
    float Gv[8] = {G0.x, G0.y, G0.z, G0.w, G1.x, G1.y, G1.z, G1.w};
    float Bv[8] = {B0.x, B0.y, B0.z, B0.w, B1v.x, B1v.y, B1v.z, B1v.w};
    float z[8];
#pragma unroll
    for (int i = 0; i < 8; i++) z[i] = (y[i] - mean2) * inv2 * Gv[i] + Bv[i];
    if (M2 == 6) {
        uint16_t* o = (uint16_t*)out2 + (size_t)row * DD;
        uint2 p0, p1;
        p0.x = (uint32_t)f2bf(z[0]) | ((uint32_t)f2bf(z[1]) << 16);
        p0.y = (uint32_t)f2bf(z[2]) | ((uint32_t)f2bf(z[3]) << 16);
        p1.x = (uint32_t)f2bf(z[4]) | ((uint32_t)f2bf(z[5]) << 16);
        p1.y = (uint32_t)f2bf(z[6]) | ((uint32_t)f2bf(z[7]) << 16);
        *(uint2*)&o[lane * 4]       = p0;
        *(uint2*)&o[256 + lane * 4] = p1;
    } else {
        const float* sp = spk + (size_t)(row >> 11) * DD;
        float4 s0 = *(const float4*)&sp[lane * 4];
        float4 s1 = *(const float4*)&sp[256 + lane * 4];
        float* o = (float*)out2 + (size_t)row * DD;
        *(float4*)&o[lane * 4]       = make_float4(z[0]+s0.x, z[1]+s0.y, z[2]+s0.z, z[3]+s0.w);
        *(float4*)&o[256 + lane * 4] = make_float4(z[4]+s1.x, z[5]+s1.y, z[6]+s1.z, z[7]+s1.w);
    }
}

// ---------------- fused GLU(+skip into X) + LN -> bf16 ----------------------
__global__ void k_gluln(const uint16_t* __restrict__ H, float* __restrict__ X,
                        uint16_t* __restrict__ out,
                        const float* __restrict__ gam, const float* __restrict__ bet) {
    int row  = blockIdx.x * 4 + (threadIdx.x >> 6);
    int lane = threadIdx.x & 63;
    const uint16_t* hr = H + (size_t)row * 1024;
    uint2 ha0 = *(const uint2*)&hr[lane * 4];
    uint2 ha1 = *(const uint2*)&hr[256 + lane * 4];
    uint2 hg0 = *(const uint2*)&hr[512 + lane * 4];
    uint2 hg1 = *(const uint2*)&hr[768 + lane * 4];
    uint32_t aw[4] = {ha0.x, ha0.y, ha1.x, ha1.y};
    uint32_t gw[4] = {hg0.x, hg0.y, hg1.x, hg1.y};
    float* xr = X + (size_t)row * DD;
    float4 x0 = *(const float4*)&xr[lane * 4];
    float4 x1 = *(const float4*)&xr[256 + lane * 4];
    float xv[8] = {x0.x, x0.y, x0.z, x0.w, x1.x, x1.y, x1.z, x1.w};
    float v[8];
#pragma unroll
    for (int p = 0; p < 4; p++) {
        float a0 = bf2f(aw[p] & 0xffffu), a1 = bf2f(aw[p] >> 16);
        float g0 = bf2f(gw[p] & 0xffffu), g1 = bf2f(gw[p] >> 16);
        v[2*p]   = xv[2*p]   + a0 * sigm(g0);
        v[2*p+1] = xv[2*p+1] + a1 * sigm(g1);
    }
    *(float4*)&xr[lane * 4]       = make_float4(v[0], v[1], v[2], v[3]);
    *(float4*)&xr[256 + lane * 4] = make_float4(v[4], v[5], v[6], v[7]);
    float s = 0.f, q = 0.f;
#pragma unroll
    for (int i = 0; i < 8; i++) { s += v[i]; q += v[i] * v[i]; }
#pragma unroll
    for (int m = 1; m < 64; m <<= 1) { s += __shfl_xor(s, m); q += __shfl_xor(q, m); }
    float mean = s * (1.0f / 512.0f);
    float var  = fmaxf(q * (1.0f / 512.0f) - mean * mean, 0.0f);
    float inv  = rsqrtf(var + 1e-5f);
    float4 g0 = *(const float4*)&gam[lane * 4];
    float4 g1 = *(const float4*)&gam[256 + lane * 4];
    float4 b0 = *(const float4*)&bet[lane * 4];
    float4 b1 = *(const float4*)&bet[256 + lane * 4];
    float gv[8] = {g0.x, g0.y, g0.z, g0.w, g1.x, g1.y, g1.z, g1.w};
    float bv[8] = {b0.x, b0.y, b0.z, b0.w, b1.x, b1.y, b1.z, b1.w};
    uint16_t* o = out + (size_t)row * DD;
    uint2 p0, p1;
    float y0 = (v[0]-mean)*inv*gv[0]+bv[0], y1 = (v[1]-mean)*inv*gv[1]+bv[1];
    float y2 = (v[2]-mean)*inv*gv[2]+bv[2], y3 = (v[3]-mean)*inv*gv[3]+bv[3];
    float y4 = (v[4]-mean)*inv*gv[4]+bv[4], y5 = (v[5]-mean)*inv*gv[5]+bv[5];
    float y6 = (v[6]-mean)*inv*gv[6]+bv[6], y7 = (v[7]-mean)*inv*gv[7]+bv[7];
    p0.x = (uint32_t)f2bf(y0) | ((uint32_t)f2bf(y1) << 16);
    p0.y = (uint32_t)f2bf(y2) | ((uint32_t)f2bf(y3) << 16);
    p1.x = (uint32_t)f2bf(y4) | ((uint32_t)f2bf(y5) << 16);
    p1.y = (uint32_t)f2bf(y6) | ((uint32_t)f2bf(y7) << 16);
    *(uint2*)&o[lane * 4]       = p0;
    *(uint2*)&o[256 + lane * 4] = p1;
}

// ---------------- MFMA GEMM: 4 waves (2x2), per-wave 128x(BN/2), BK=32 ------
// Register blocking up: per-wave 128x128 (BN=256) reads 16KB LDS per 1.05
// MFLOP vs 12KB per 0.52 MFLOP previously (1.5x fewer LDS bytes/FLOP -- the
// R4-R7-fitted LDS-read-BW bottleneck). R5-proven 2-phase dbuf sync; identity
// lane mapping (0 bank conflicts); R7 chunked XCD swizzle (FETCH-verified).
// MODE 0: gelu->bf16  1: ->bf16  2: X+=0.5v  3: X+=v  4: outf32=X+0.5v
//      5: X=v         6: glu-pairs->bf16 [M][512] (interleaved weights)
template <int MODE, int BN>
__global__ __launch_bounds__(256, 1) void k_gemm4(
    const uint16_t* __restrict__ A, const uint16_t* __restrict__ Bt,
    const float* __restrict__ bias, int M, int N, int K,
    void* __restrict__ outp, float* __restrict__ X) {
    constexpr int MR = 8;                 // 128 rows / 16
    constexpr int NR = BN / 32;           // 8 (BN=256) or 4 (BN=128)
    constexpr int ABLK = 16;              // 1KB blocks per A K-step tile
    constexpr int BBLK = BN / 16;         // 16 or 8
    constexpr int APW = 4;                // A blocks staged per wave
    constexpr int BPW = BBLK / 4;         // 4 or 2
    __shared__ __align__(16) uint16_t As[2][ABLK * 512];
    __shared__ __align__(16) uint16_t Bs[2][BBLK * 512];
    int tid = threadIdx.x;
    int wave = tid >> 6, lane = tid & 63;
    int l15 = lane & 15, l16 = lane >> 4;
    int wr = wave >> 1, wc = wave & 1;

    // chunked XCD-bijective swizzle (nbx=64, grids multiple of 8)
    int nbx  = M >> 8;
    int nbxq = nbx >> 3;
    int x8 = blockIdx.x & 7, jj = blockIdx.x >> 3;
    int bx = x8 * nbxq + (jj % nbxq);
    int by = jj / nbxq;
    int m0 = bx * 256, n0 = by * BN;

    const uint16_t* srcA[APW];
    const uint16_t* srcB[BPW];
#pragma unroll
    for (int p = 0; p < APW; p++) {
        int bi = wave * APW + p;
        srcA[p] = A + (size_t)(m0 + bi * 16 + l15) * K + l16 * 8;
    }
#pragma unroll
    for (int p = 0; p < BPW; p++) {
        int bi = wave * BPW + p;
        srcB[p] = Bt + (size_t)(n0 + bi * 16 + l15) * K + l16 * 8;
    }

    f32x4 acc[MR][NR];
#pragma unroll
    for (int i = 0; i < MR; i++)
#pragma unroll
        for (int j = 0; j < NR; j++) acc[i][j] = (f32x4){0.f, 0.f, 0.f, 0.f};

    auto STAGE = [&](int tt) {
        int b = tt & 1;
        int kof = tt << 5;
#pragma unroll
        for (int p = 0; p < APW; p++)
            gload16(srcA[p] + kof, &As[b][(wave * APW + p) * 512]);
#pragma unroll
        for (int p = 0; p < BPW; p++)
            gload16(srcB[p] + kof, &Bs[b][(wave * BPW + p) * 512]);
    };

    int nk = K >> 5;
    STAGE(0);
    __syncthreads();
    for (int t = 0; t < nk; ++t) {
        int buf = t & 1;
        if (t + 1 < nk) STAGE(t + 1);
        s16x8 af[MR], bfr[NR];
#pragma unroll
        for (int i = 0; i < MR; i++)
            af[i] = *(const s16x8*)&As[buf][(wr * MR + i) * 512 + lane * 8];
#pragma unroll
        for (int j = 0; j < NR; j++)
            bfr[j] = *(const s16x8*)&Bs[buf][(wc * NR + j) * 512 + lane * 8];
#pragma unroll
        for (int i = 0; i < MR; i++)
#pragma unroll
            for (int j = 0; j < NR; j++)
                acc[i][j] = __builtin_amdgcn_mfma_f32_16x16x32_bf16(af[i], bfr[j], acc[i][j], 0, 0, 0);
        __syncthreads();                  // drains prefetch + read hazards
    }
    // epilogue: D frag col=l15, row=l16*4+q
#pragma unroll
    for (int i = 0; i < MR; i++) {
#pragma unroll
        for (int j = 0; j < NR; j++) {
            int gcol = n0 + wc * NR * 16 + j * 16 + l15;
            float bv = bias[gcol];
#pragma unroll
            for (int q = 0; q < 4; q++) {
                int grow = m0 + wr * MR * 16 + i * 16 + l16 * 4 + q;
                float v = acc[i][j][q] + bv;
                if (MODE == 0) {
                    ((uint16_t*)outp)[(size_t)grow * N + gcol] = f2bf(gelu_f(v));
                } else if (MODE == 1) {
                    ((uint16_t*)outp)[(size_t)grow * N + gcol] = f2bf(v);
                } else if (MODE == 2) {
                    X[(size_t)grow * DD + gcol] += 0.5f * v;
                } else if (MODE == 3) {
                    X[(size_t)grow * DD + gcol] += v;
                } else if (MODE == 4) {
                    ((float*)outp)[(size_t)grow * DD + gcol] =
                        X[(size_t)grow * DD + gcol] + 0.5f * v;
                } else if (MODE == 5) {
                    X[(size_t)grow * DD + gcol] = v;
                } else {
                    // MODE 6: interleaved GLU pairs. even col = a, odd = g.
                    float g = __shfl_xor(v, 1);
                    if ((l15 & 1) == 0) {
                        ((uint16_t*)outp)[(size_t)grow * DD + (gcol >> 1)] =
                            f2bf(v * sigm(g));
                    }
                }
            }
        }
    }
}

// ---------------- bf16 transpose [R][C] -> [C][R] per batch z ---------------
__global__ void k_tpose(const uint16_t* __restrict__ in, uint16_t* __restrict__ out,
                        int R, int C) {
    __shared__ uint16_t tile[32][34];
    size_t boff = (size_t)blockIdx.z * R * C;
    int c0 = blockIdx.x * 32, r0 = blockIdx.y * 32;
    int tx = threadIdx.x, ty = threadIdx.y;
#pragma unroll
    for (int i = 0; i < 4; i++)
        tile[ty + i * 8][tx] = in[boff + (size_t)(r0 + ty + i * 8) * C + c0 + tx];
    __syncthreads();
#pragma unroll
    for (int i = 0; i < 4; i++)
        out[boff + (size_t)(c0 + ty + i * 8) * R + r0 + tx] = tile[tx][ty + i * 8];
}

// ===================== DSS chunked-scan machinery ===========================
__global__ __launch_bounds__(64) void k_phiprep(
        const float* __restrict__ lam_re, const float* __restrict__ lam_im,
        const float* __restrict__ log_dt, uint16_t* __restrict__ PHI,
        float* __restrict__ A64f) {
    int l = blockIdx.x, n = threadIdx.x;
    float dt = expf(log_dt[l]);
    float lr = lam_re[l * 64 + n], li = lam_im[l * 64 + n];
    float mag = expf(-expf(lr) * dt), th = li * dt;
    float Are = mag * __cosf(th), Aim = mag * __sinf(th);
    float Pre = 1.f, Pim = 0.f;
    uint16_t* ph = PHI + (size_t)l * 8192;
    for (int tau = 0; tau < 64; tau++) {
        int s = 63 - tau;
        ph[n * 64 + s]        = f2bf(Pre);
        ph[(64 + n) * 64 + s] = f2bf(Pim);
        float nr = Pre * Are - Pim * Aim;
        float ni = Pre * Aim + Pim * Are;
        Pre = nr; Pim = ni;
    }
    A64f[l * 128 + 2 * n]     = Pre;
    A64f[l * 128 + 2 * n + 1] = Pim;
}

__global__ __launch_bounds__(64) void k_gprep(
        const float* __restrict__ lam_re, const float* __restrict__ lam_im,
        const float* __restrict__ c_re, const float* __restrict__ c_im,
        const float* __restrict__ ssm_d, const float* __restrict__ log_dt,
        int l, uint16_t* __restrict__ G) {
    int h = blockIdx.x, n = threadIdx.x;
    __shared__ float klds[64];
    float dt = expf(log_dt[l]);
    float lr = lam_re[l * 64 + n], li = lam_im[l * 64 + n];
    float mag = expf(-expf(lr) * dt), th = li * dt;
    float Are = mag * __cosf(th), Aim = mag * __sinf(th);
    float Cre = c_re[(size_t)l * DD * 64 + h * 64 + n];
    float Cim = c_im[(size_t)l * DD * 64 + h * 64 + n];
    uint16_t* Gh = G + (size_t)h * 64 * 192;
    float Pre = 1.f, Pim = 0.f;
    for (int r = 0; r < 64; r++) {
        float t = Cre * Pre - Cim * Pim;
        float s = t;
        s += __shfl_xor(s, 1);  s += __shfl_xor(s, 2);  s += __shfl_xor(s, 4);
        s += __shfl_xor(s, 8);  s += __shfl_xor(s, 16); s += __shfl_xor(s, 32);
        if (n == 0) klds[r] = dt * s;
        float nr = Pre * Are - Pim * Aim;
        float ni = Pre * Aim + Pim * Are;
        float wre = dt * (Cre * nr - Cim * ni);
        float wim = dt * (Cre * ni + Cim * nr);
        Gh[r * 192 + 64 + n]  = f2bf(wre);
        Gh[r * 192 + 128 + n] = f2bf(-wim);
        Pre = nr; Pim = ni;
    }
    __syncthreads();
    float dh = ssm_d[l * DD + h];
    for (int r = 0; r < 64; r++) {
        int c = n;
        float val = (c < r) ? klds[r - c] : (c == r ? klds[0] + dh : 0.f);
        Gh[r * 192 + c] = f2bf(val);
    }
}

// pass1: E[col][128] = Phi[128x64] @ u-chunks
__global__ __launch_bounds__(256) void k_pass1(
        const uint16_t* __restrict__ u, const uint16_t* __restrict__ PHI,
        uint16_t* __restrict__ E) {
    __shared__ __align__(16) uint16_t Phs[128 * 72];
    int tid = threadIdx.x;
    for (int v = tid; v < 1024; v += 256) {
        int row = v >> 3, kb = v & 7;
        *(s16x8*)&Phs[row * 72 + kb * 8] = *(const s16x8*)&PHI[row * 64 + kb * 8];
    }
    __syncthreads();
    int wave = tid >> 6, lane = tid & 63;
    int l15 = lane & 15, l16 = lane >> 4;
    int m0 = (wave & 1) * 64;
    int colbase = blockIdx.x * 128 + (wave >> 1) * 64;
    f32x4 acc[4][4];
#pragma unroll
    for (int i = 0; i < 4; i++)
#pragma unroll
        for (int j = 0; j < 4; j++) acc[i][j] = (f32x4){0.f, 0.f, 0.f, 0.f};
#pragma unroll
    for (int kt = 0; kt < 64; kt += 32) {
        s16x8 a[4], b[4];
#pragma unroll
        for (int i = 0; i < 4; i++)
            a[i] = *(const s16x8*)&Phs[(m0 + i * 16 + l15) * 72 + kt + l16 * 8];
#pragma unroll
        for (int j = 0; j < 4; j++)
            b[j] = *(const s16x8*)(u + (size_t)(colbase + j * 16 + l15) * 64 + kt + l16 * 8);
#pragma unroll
        for (int i = 0; i < 4; i++)
#pragma unroll
            for (int j = 0; j < 4; j++)
                acc[i][j] = __builtin_amdgcn_mfma_f32_16x16x32_bf16(a[i], b[j], acc[i][j], 0, 0, 0);
    }
#pragma unroll
    for (int i = 0; i < 4; i++)
#pragma unroll
        for (int j = 0; j < 4; j++) {
            int col = colbase + j * 16 + l15;
            int r0  = m0 + i * 16 + l16 * 4;
            uint32_t p0 = (uint32_t)f2bf(acc[i][j][0]) | ((uint32_t)f2bf(acc[i][j][1]) << 16);
            uint32_t p1 = (uint32_t)f2bf(acc[i][j][2]) | ((uint32_t)f2bf(acc[i][j][3]) << 16);
            *(uint2*)&E[(size_t)col * 128 + r0] = make_uint2(p0, p1);
        }
}

// pass2: chunk-boundary states
__global__ void k_pass2(const uint16_t* __restrict__ E, const float* __restrict__ A64f,
                        int l, uint16_t* __restrict__ Sp) {
    int gid = blockIdx.x * 256 + threadIdx.x;
    int n = gid & 63, bh = gid >> 6;
    int b = bh >> 9, h = bh & 511;
    float2 A = *(const float2*)&A64f[l * 128 + 2 * n];
    float Sre = 0.f, Sim = 0.f;
    const uint16_t* Eb = E + (size_t)bh * 32 * 128;
    uint16_t* So = Sp + (size_t)h * 32768 + (size_t)b * 32 * 128;
    for (int i = 0; i < 32; i++) {
        So[i * 128 + n]      = f2bf(Sre);
        So[i * 128 + 64 + n] = f2bf(Sim);
        float er = bf2f((uint32_t)Eb[i * 128 + n]);
        float ei = bf2f((uint32_t)Eb[i * 128 + 64 + n]);
        float nr = A.x * Sre - A.y * Sim + er;
        float ni = A.x * Sim + A.y * Sre + ei;
        Sre = nr; Sim = ni;
    }
}

// pass3: per-h GEMM  Y[64 x 256cols] = G_h[64x192] @ [u;Sre;Sim]
__global__ __launch_bounds__(256) void k_pass3(
        const uint16_t* __restrict__ G, const uint16_t* __restrict__ u,
        const uint16_t* __restrict__ Sp, uint16_t* __restrict__ Y) {
    __shared__ __align__(16) uint16_t Gs[64 * 200];
    int h = blockIdx.x, tid = threadIdx.x;
    for (int v = tid; v < 1536; v += 256) {
        int row = v / 24, kb = v % 24;
        *(s16x8*)&Gs[row * 200 + kb * 8] = *(const s16x8*)&G[(size_t)h * 12288 + row * 192 + kb * 8];
    }
    __syncthreads();
    int wave = tid >> 6, lane = tid & 63;
    int l15 = lane & 15, l16 = lane >> 4;
    int wn = wave * 64;
    const uint16_t* uh = u + (size_t)h * TT;
    const uint16_t* sh = Sp + (size_t)h * 32768;
    f32x4 acc[4][4];
#pragma unroll
    for (int i = 0; i < 4; i++)
#pragma unroll
        for (int j = 0; j < 4; j++) acc[i][j] = (f32x4){0.f, 0.f, 0.f, 0.f};
#pragma unroll
    for (int kt = 0; kt < 192; kt += 32) {
        s16x8 a[4], b[4];
#pragma unroll
        for (int i = 0; i < 4; i++)
            a[i] = *(const s16x8*)&Gs[(i * 16 + l15) * 200 + kt + l16 * 8];
#pragma unroll
        for (int j = 0; j < 4; j++) {
            int col = wn + j * 16 + l15;
            const uint16_t* src;
            if (kt < 64)
                src = uh + (size_t)(col >> 5) * (DD * TT) + (col & 31) * 64 + kt + l16 * 8;
            else
                src = sh + (size_t)col * 128 + (kt - 64) + l16 * 8;
            b[j] = *(const s16x8*)src;
        }
#pragma unroll
        for (int i = 0; i < 4; i++)
#pragma unroll
            for (int j = 0; j < 4; j++)
                acc[i][j] = __builtin_amdgcn_mfma_f32_16x16x32_bf16(a[i], b[j], acc[i][j], 0, 0, 0);
    }
#pragma unroll
    for (int i = 0; i < 4; i++)
#pragma unroll
        for (int j = 0; j < 4; j++) {
            int col = wn + j * 16 + l15;
            int r0  = i * 16 + l16 * 4;
            uint16_t* dst = Y + (size_t)(col >> 5) * (DD * TT) + (size_t)h * TT + (col & 31) * 64 + r0;
            uint32_t p0 = (uint32_t)f2bf(acc[i][j][0]) | ((uint32_t)f2bf(acc[i][j][1]) << 16);
            uint32_t p1 = (uint32_t)f2bf(acc[i][j][2]) | ((uint32_t)f2bf(acc[i][j][3]) << 16);
            *(uint2*)&dst[0] = make_uint2(p0, p1);
        }
}

// ---------------- gelu + transpose [b][h][t] -> [b][t][h] -------------------
__global__ void k_tgelu(const uint16_t* __restrict__ y, uint16_t* __restrict__ out) {
    __shared__ uint16_t tile[32][34];
    int b = blockIdx.z;
    int t0 = blockIdx.x * 32, h0 = blockIdx.y * 32;
    int tx = threadIdx.x, ty = threadIdx.y;
    const uint16_t* yb = y + (size_t)b * DD * TT;
#pragma unroll
    for (int i = 0; i < 4; i++) {
        int h = h0 + ty + i * 8;
        tile[ty + i * 8][tx] = f2bf(gelu_f(bf2f((uint32_t)yb[(size_t)h * TT + t0 + tx])));
    }
    __syncthreads();
    uint16_t* ob = out + (size_t)b * TT * DD;
#pragma unroll
    for (int i = 0; i < 4; i++) {
        int t = t0 + ty + i * 8;
        ob[(size_t)t * DD + h0 + tx] = tile[tx][ty + i * 8];
    }
}

// ---------------- fused depthwise conv k=31 + LN + gelu -> bf16 -------------
__global__ __launch_bounds__(256) void k_dwln(
        const uint16_t* __restrict__ in, const float* __restrict__ dwt,
        const float* __restrict__ db, const float* __restrict__ gam,
        const float* __restrict__ bet, uint16_t* __restrict__ out) {
    __shared__ __align__(16) uint16_t xs[34 * 512];
    __shared__ float red[4][4][2];
    int tid = threadIdx.x;
    int t0 = (blockIdx.x & 511) * 4;
    int b  = blockIdx.x >> 9;
    const uint16_t* ib = in + (size_t)b * TT * DD;
    for (int v = tid; v < 34 * 64; v += 256) {
        int row = v >> 6, seg = v & 63;
        int tj = t0 - 15 + row;
        uint4 val = make_uint4(0, 0, 0, 0);
        if (tj >= 0 && tj < TT) val = *(const uint4*)&ib[(size_t)tj * DD + seg * 8];
        *(uint4*)&xs[row * 512 + seg * 8] = val;
    }
    __syncthreads();
    int d = tid * 2;
    int wave = tid >> 6, lane = tid & 63;
    float a0[4], a1[4];
    float bv0 = db[d], bv1 = db[d + 1];
#pragma unroll
    for (int o = 0; o < 4; o++) { a0[o] = bv0; a1[o] = bv1; }
#pragma unroll
    for (int k = 0; k < 31; k++) {
        float2 w = *(const float2*)&dwt[k * DD + d];
#pragma unroll
        for (int o = 0; o < 4; o++) {
            uint32_t v = *(const uint32_t*)&xs[(o + k) * 512 + d];
            a0[o] = fmaf(bf2f(v & 0xffffu), w.x, a0[o]);
            a1[o] = fmaf(bf2f(v >> 16), w.y, a1[o]);
        }
    }
#pragma unroll
    for (int o = 0; o < 4; o++) {
        float ss = a0[o] + a1[o];
        float qq = a0[o] * a0[o] + a1[o] * a1[o];
#pragma unroll
        for (int m = 1; m < 64; m <<= 1) { ss += __shfl_xor(ss, m); qq += __shfl_xor(qq, m); }
        if (lane == 0) { red[o][wave][0] = ss; red[o][wave][1] = qq; }
    }
    __syncthreads();
    float g0 = gam[d], g1 = gam[d + 1], be0 = bet[d], be1 = bet[d + 1];
#pragma unroll
    for (int o = 0; o < 4; o++) {
        float s = red[o][0][0] + red[o][1][0] + red[o][2][0] + red[o][3][0];
        float q = red[o][0][1] + red[o][1][1] + red[o][2][1] + red[o][3][1];
        float mean = s * (1.0f / 512.0f);
        float var  = fmaxf(q * (1.0f / 512.0f) - mean * mean, 0.0f);
        float inv  = rsqrtf(var + 1e-5f);
        float y0 = gelu_f((a0[o] - mean) * inv * g0 + be0);
        float y1 = gelu_f((a1[o] - mean) * inv * g1 + be1);
        uint32_t p = (uint32_t)f2bf(y0) | ((uint32_t)f2bf(y1) << 16);
        *(uint32_t*)&out[((size_t)b * TT + t0 + o) * DD + d] = p;
    }
}

// ---------------------------------------------------------------------------
extern "C" void kernel_launch(void* const* d_in, const int* in_sizes, int n_in,
                              void* d_out, int out_size, void* d_ws, size_t ws_size,
                              hipStream_t stream) {
    const float* src        = (const float*)d_in[0];
    const float* speaker    = (const float*)d_in[1];
    const float* src_w      = (const float*)d_in[2];
    const float* src_b      = (const float*)d_in[3];
    const float* ffn1_ln_g  = (const float*)d_in[4];
    const float* ffn1_ln_b  = (const float*)d_in[5];
    const float* ffn1_w1    = (const float*)d_in[6];
    const float* ffn1_b1    = (const float*)d_in[7];
    const float* ffn1_w2    = (const float*)d_in[8];
    const float* ffn1_b2    = (const float*)d_in[9];
    const float* norm1_g    = (const float*)d_in[10];
    const float* norm1_b    = (const float*)d_in[11];
    const float* lam_re     = (const float*)d_in[12];
    const float* lam_im     = (const float*)d_in[13];
    const float* c_re       = (const float*)d_in[14];
    const float* c_im       = (const float*)d_in[15];
    const float* ssm_d      = (const float*)d_in[16];
    const float* log_dt     = (const float*)d_in[17];
    const float* dss_out_w  = (const float*)d_in[18];
    const float* dss_out_b  = (const float*)d_in[19];
    const float* conv_ln_g  = (const float*)d_in[20];
    const float* conv_ln_b  = (const float*)d_in[21];
    const float* bneck_w    = (const float*)d_in[22];
    const float* bneck_b    = (const float*)d_in[23];
    const float* dw_w       = (const float*)d_in[24];
    const float* dw_b       = (const float*)d_in[25];
    const float* conv_ln2_g = (const float*)d_in[26];
    const float* conv_ln2_b = (const float*)d_in[27];
    const float* conv_lin_w = (const float*)d_in[28];
    const float* conv_lin_b = (const float*)d_in[29];
    const float* ffn2_ln_g  = (const float*)d_in[30];
    const float* ffn2_ln_b  = (const float*)d_in[31];
    const float* ffn2_w1    = (const float*)d_in[32];
    const float* ffn2_b1    = (const float*)d_in[33];
    const float* ffn2_w2    = (const float*)d_in[34];
    const float* ffn2_b2    = (const float*)d_in[35];
    const float* norm2_g    = (const float*)d_in[36];
    const float* norm2_b    = (const float*)d_in[37];
    const float* final_g    = (const float*)d_in[38];
    const float* final_b    = (const float*)d_in[39];
    (void)in_sizes; (void)n_in; (void)out_size; (void)ws_size;

    uint8_t* ws = (uint8_t*)d_ws;
    float*    X   = (float*)   (ws + 0);                     // f32 [16384][512]
    float*    F0  = (float*)   (ws + 33554432);              // f32 [16384][512] / Spack
    uint16_t* B1  = (uint16_t*)(ws + 67108864);              // bf16 [16384][512] / G
    uint16_t* B2  = (uint16_t*)(ws + 83886080);              // bf16 u / Wsrc
    uint16_t* B3  = (uint16_t*)(ws + 100663296);             // bf16 y / src_bf16
    uint16_t* H   = (uint16_t*)(ws + 117440512);             // bf16 GEMM mids / E
    uint16_t* Wf1a= (uint16_t*)(ws + 184549376);
    uint16_t* Wf1b= (uint16_t*)(ws + 197132288);
    uint16_t* Wds = (uint16_t*)(ws + 209715200);
    uint16_t* Wbn = (uint16_t*)(ws + 216006656);             // interleaved GLU weights
    uint16_t* Wcl = (uint16_t*)(ws + 222298112);
    uint16_t* Wf2a= (uint16_t*)(ws + 225443840);
    uint16_t* Wf2b= (uint16_t*)(ws + 238026752);
    float*    DWT = (float*)   (ws + 250609664);
    uint16_t* PHI = (uint16_t*)(ws + 250990592);
    float*    A64f= (float*)   (ws + 251088896);
    float*    BNB = (float*)   (ws + 251092992);             // interleaved bneck bias [L][1024]

    uint16_t* GBUF = B1;
    uint16_t* SPK  = (uint16_t*)F0;
    uint16_t* EBUF = H;
    uint16_t* SRCB = B3;                                     // src bf16 [16384][128]
    uint16_t* WSRC = B2;                                     // src_w bf16 [512][128]

    dim3 tb(32, 8);
    k_wtrans<<<dim3(FF/32, DD/32, NL), tb, 0, stream>>>(ffn1_w1, Wf1a, DD, FF);
    k_wtrans<<<dim3(DD/32, FF/32, NL), tb, 0, stream>>>(ffn1_w2, Wf1b, FF, DD);
    k_wtrans<<<dim3(1024/32, DD/32, NL), tb, 0, stream>>>(dss_out_w, Wds, DD, 1024);
    k_wglu<<<(NL*1024*DD + 255)/256, 256, 0, stream>>>(bneck_w, bneck_b, Wbn, BNB);
    k_wcvt<<<(NL*DD*DD + 255)/256, 256, 0, stream>>>(conv_lin_w, Wcl, NL*DD*DD);
    k_wtrans<<<dim3(FF/32, DD/32, NL), tb, 0, stream>>>(ffn2_w1, Wf2a, DD, FF);
    k_wtrans<<<dim3(DD/32, FF/32, NL), tb, 0, stream>>>(ffn2_w2, Wf2b, FF, DD);
    k_dwt<<<(NL*DD*31 + 255)/256, 256, 0, stream>>>(dw_w, DWT);
    k_phiprep<<<NL, 64, 0, stream>>>(lam_re, lam_im, log_dt, PHI, A64f);
    k_srcpad<<<(ROWS*128 + 255)/256, 256, 0, stream>>>(src, SRCB);
    k_wsrcpad<<<(DD*128 + 255)/256, 256, 0, stream>>>(src_w, WSRC);

    // input projection: X = src @ W + b  (K padded to 128, N=512 -> BN=128)
    k_gemm4<5,128><<<256, 256, 0, stream>>>(SRCB, WSRC, src_b, ROWS, DD, 128, nullptr, X);
    // first ffn1 LN
    k_ln<0><<<4096, 256, 0, stream>>>(X, B1, ffn1_ln_g, ffn1_ln_b, nullptr, 1e-5f);

    for (int l = 0; l < NL; l++) {
        // 1. FFN1 (B1 = LN(x) precomputed)
        k_gemm4<0,256><<<512, 256, 0, stream>>>(B1, Wf1a + (size_t)l*FF*DD, ffn1_b1 + l*FF,
                                                ROWS, FF, DD, H, nullptr);
        k_gemm4<2,128><<<256, 256, 0, stream>>>(H, Wf1b + (size_t)l*DD*FF, ffn1_b2 + l*DD,
                                                ROWS, DD, FF, nullptr, X);
        // 2. DSS
        k_ln<0><<<4096, 256, 0, stream>>>(X, B1, norm1_g + l*DD, norm1_b + l*DD, nullptr, 1e-5f);
        k_tpose<<<dim3(DD/32, TT/32, BB), tb, 0, stream>>>(B1, B2, TT, DD);
        k_gprep<<<DD, 64, 0, stream>>>(lam_re, lam_im, c_re, c_im, ssm_d, log_dt, l, GBUF);
        k_pass1<<<1024, 256, 0, stream>>>(B2, PHI + (size_t)l*8192, EBUF);
        k_pass2<<<1024, 256, 0, stream>>>(EBUF, A64f, l, SPK);
        k_pass3<<<DD, 256, 0, stream>>>(GBUF, B2, SPK, B3);
        k_tgelu<<<dim3(TT/32, DD/32, BB), tb, 0, stream>>>(B3, B1);
        k_gemm4<1,256><<<256, 256, 0, stream>>>(B1, Wds + (size_t)l*1024*DD, dss_out_b + l*1024,
                                                ROWS, 1024, DD, H, nullptr);
        // fused GLU(+skip) + conv LN
        k_gluln<<<4096, 256, 0, stream>>>(H, X, B1, conv_ln_g + l*DD, conv_ln_b + l*DD);
        // 3. Conv module (GLU fused into bneck GEMM epilogue via MODE 6)
        k_gemm4<6,256><<<256, 256, 0, stream>>>(B1, Wbn + (size_t)l*1024*DD, BNB + l*1024,
                                                ROWS, 1024, DD, B2, nullptr);
        k_dwln<<<BB*512, 256, 0, stream>>>(B2, DWT + (size_t)l*31*DD, dw_b + l*DD,
                                           conv_ln2_g + l*DD, conv_ln2_b + l*DD, B1);
        k_gemm4<3,128><<<256, 256, 0, stream>>>(B1, Wcl + (size_t)l*DD*DD, conv_lin_b + l*DD,
                                                ROWS, DD, DD, nullptr, X);
        // 4. FFN2
        k_ln<0><<<4096, 256, 0, stream>>>(X, B1, ffn2_ln_g + l*DD, ffn2_ln_b + l*DD, nullptr, 1e-5f);
        k_gemm4<0,256><<<512, 256, 0, stream>>>(B1, Wf2a + (size_t)l*FF*DD, ffn2_b1 + l*FF,
                                                ROWS, FF, DD, H, nullptr);
        k_gemm4<4,128><<<256, 256, 0, stream>>>(H, Wf2b + (size_t)l*DD*FF, ffn2_b2 + l*DD,
                                                ROWS, DD, FF, F0, X);
        // norm2 (+ next-layer ffn1 LN, or final LN + speaker)
        if (l < NL - 1) {
            k_ln2<6><<<4096, 256, 0, stream>>>(F0, X, B1, norm2_g + l*DD, norm2_b + l*DD,
                                               ffn1_ln_g + (l+1)*DD, ffn1_ln_b + (l+1)*DD,
                                               nullptr, 1e-5f);
        } else {
            k_ln2<7><<<4096, 256, 0, stream>>>(F0, nullptr, d_out, norm2_g + l*DD, norm2_b + l*DD,
                                               final_g, final_b, speaker, 1e-6f);
        }
    }
}

// Round 9
// 3143.037 us; speedup vs baseline: 1.3257x; 1.3257x over previous
//
#include <hip/hip_runtime.h>
#include <hip/hip_bf16.h>
#include <stdint.h>

// ---------------------------------------------------------------------------
// S4 / Conformer-style encoder, 6 layers. B=8 T=2048 D=512 F=2048 N=64 K=31
// R9: revert GEMM to R5-exact 256-tile 2-phase (proven 84us FFN-a; R8's
// 4-wave register blocking hit the 1-wave/SIMD occupancy cliff). Add: fine
// interleave of stage-halves between MFMA k-sub clusters (no sync change);
// GLU fused in bneck epilogue (MODE 6, verified R8); dwconv 16 rows/block
// (read amp 8.5x -> 2.9x).
// ---------------------------------------------------------------------------

#define NL 6
#define TT 2048
#define BB 8
#define DD 512
#define FF 2048
#define ROWS (BB*TT)          // 16384

typedef __attribute__((ext_vector_type(4))) float f32x4;
typedef __attribute__((ext_vector_type(8))) short s16x8;

#define DEVI __device__ __forceinline__

DEVI float bf2f(uint32_t u) { union { uint32_t i; float f; } v; v.i = u << 16; return v.f; }
DEVI uint16_t f2bf(float f) {
    union { float f; uint32_t i; } v; v.f = f;
    uint32_t x = v.i;
    return (uint16_t)((x + 0x7fffu + ((x >> 16) & 1u)) >> 16);   // RNE
}
// tanh-approx gelu == x * sigmoid(1.59577x + 0.0713548x^3)
DEVI float gelu_f(float x) {
    float x2 = x * x;
    float z  = x * fmaf(x2, 0.07135481627f, 1.5957691216f);
    return x * __builtin_amdgcn_rcpf(1.0f + __expf(-z));
}
DEVI float sigm(float x) { return __builtin_amdgcn_rcpf(1.0f + __expf(-x)); }

// async global->LDS, 16B/lane; dest = wave-uniform base, HW adds lane*16
DEVI void gload16(const uint16_t* g, uint16_t* l) {
    __builtin_amdgcn_global_load_lds((const __attribute__((address_space(1))) void*)g,
                                     (__attribute__((address_space(3))) void*)l, 16, 0, 0);
}

// ---------------- weight prep ----------------------------------------------
__global__ void k_wtrans(const float* __restrict__ src, uint16_t* __restrict__ dst,
                         int K, int N) {
    __shared__ float tile[32][33];
    int l = blockIdx.z;
    const float* s = src + (size_t)l * K * N;
    uint16_t*    d = dst + (size_t)l * N * K;
    int n0 = blockIdx.x * 32, k0 = blockIdx.y * 32;
    int tx = threadIdx.x, ty = threadIdx.y;
#pragma unroll
    for (int i = 0; i < 4; i++) {
        int k = k0 + ty + i * 8;
        tile[ty + i * 8][tx] = s[(size_t)k * N + n0 + tx];
    }
    __syncthreads();
#pragma unroll
    for (int i = 0; i < 4; i++) {
        int n = n0 + ty + i * 8;
        d[(size_t)n * K + k0 + tx] = f2bf(tile[tx][ty + i * 8]);
    }
}
__global__ void k_wcvt(const float* __restrict__ src, uint16_t* __restrict__ dst, int n) {
    int i = blockIdx.x * 256 + threadIdx.x;
    if (i < n) dst[i] = f2bf(src[i]);
}
// bneck_w [L][1024][512] -> interleaved bf16: row 2m = a-row m, 2m+1 = g-row 512+m.
// bneck_b [L][1024] -> interleaved f32 bias likewise.
__global__ void k_wglu(const float* __restrict__ w, const float* __restrict__ b,
                       uint16_t* __restrict__ wd, float* __restrict__ bd) {
    int i = blockIdx.x * 256 + threadIdx.x;
    int tot = NL * 1024 * DD;
    if (i < tot) {
        int l = i / (1024 * DD), r = (i / DD) % 1024, k = i % DD;
        int srow = (r & 1) ? (512 + (r >> 1)) : (r >> 1);
        wd[i] = f2bf(w[((size_t)l * 1024 + srow) * DD + k]);
    }
    if (i < NL * 1024) {
        int l = i >> 10, r = i & 1023;
        int srow = (r & 1) ? (512 + (r >> 1)) : (r >> 1);
        bd[i] = b[l * 1024 + srow];
    }
}
__global__ void k_dwt(const float* __restrict__ dw, float* __restrict__ dwt) {
    int i = blockIdx.x * 256 + threadIdx.x;
    int tot = NL * DD * 31;
    if (i >= tot) return;
    int l = i / (DD * 31), r = i % (DD * 31), d = r / 31, k = r % 31;
    dwt[(size_t)l * 31 * DD + k * DD + d] = dw[i];
}
// src [16384][80] f32 -> [16384][128] bf16 (zero-pad K)
__global__ void k_srcpad(const float* __restrict__ src, uint16_t* __restrict__ dst) {
    int i = blockIdx.x * 256 + threadIdx.x;
    if (i >= ROWS * 128) return;
    int r = i >> 7, c = i & 127;
    dst[i] = (c < 80) ? f2bf(src[(size_t)r * 80 + c]) : (uint16_t)0;
}
// src_w [80][512] f32 -> [512][128] bf16 transposed+padded
__global__ void k_wsrcpad(const float* __restrict__ w, uint16_t* __restrict__ dst) {
    int i = blockIdx.x * 256 + threadIdx.x;
    if (i >= DD * 128) return;
    int n = i >> 7, k = i & 127;
    dst[i] = (k < 80) ? f2bf(w[(size_t)k * DD + n]) : (uint16_t)0;
}

// ---------------- LayerNorm (wave per row) ----------------------------------
template <int MODE>
__global__ void k_ln(const float* __restrict__ in, void* __restrict__ outp,
                     const float* __restrict__ gam, const float* __restrict__ bet,
                     const float* __restrict__ spk, float eps) {
    int row  = blockIdx.x * 4 + (threadIdx.x >> 6);
    int lane = threadIdx.x & 63;
    const float* x = in + (size_t)row * DD;
    float4 a0 = *(const float4*)&x[lane * 4];
    float4 a1 = *(const float4*)&x[256 + lane * 4];
    float v[8] = {a0.x, a0.y, a0.z, a0.w, a1.x, a1.y, a1.z, a1.w};
    float s = 0.f, q = 0.f;
#pragma unroll
    for (int i = 0; i < 8; i++) { s += v[i]; q += v[i] * v[i]; }
#pragma unroll
    for (int m = 1; m < 64; m <<= 1) { s += __shfl_xor(s, m); q += __shfl_xor(q, m); }
    float mean = s * (1.0f / 512.0f);
    float var  = fmaxf(q * (1.0f / 512.0f) - mean * mean, 0.0f);
    float inv  = rsqrtf(var + eps);
    float4 g0 = *(const float4*)&gam[lane * 4];
    float4 g1 = *(const float4*)&gam[256 + lane * 4];
    float4 b0 = *(const float4*)&bet[lane * 4];
    float4 b1 = *(const float4*)&bet[256 + lane * 4];
    float gv[8] = {g0.x, g0.y, g0.z, g0.w, g1.x, g1.y, g1.z, g1.w};
    float bv[8] = {b0.x, b0.y, b0.z, b0.w, b1.x, b1.y, b1.z, b1.w};
    float y[8];
#pragma unroll
    for (int i = 0; i < 8; i++) y[i] = (v[i] - mean) * inv * gv[i] + bv[i];
    uint16_t* o = (uint16_t*)outp + (size_t)row * DD;
    uint2 p0, p1;
    p0.x = (uint32_t)f2bf(y[0]) | ((uint32_t)f2bf(y[1]) << 16);
    p0.y = (uint32_t)f2bf(y[2]) | ((uint32_t)f2bf(y[3]) << 16);
    p1.x = (uint32_t)f2bf(y[4]) | ((uint32_t)f2bf(y[5]) << 16);
    p1.y = (uint32_t)f2bf(y[6]) | ((uint32_t)f2bf(y[7]) << 16);
    *(uint2*)&o[lane * 4]       = p0;
    *(uint2*)&o[256 + lane * 4] = p1;
}

// ---------------- double-LN -------------------------------------------------
template <int M2>
__global__ void k_ln2(const float* __restrict__ in, float* __restrict__ X,
                      void* __restrict__ out2,
                      const float* __restrict__ g1, const float* __restrict__ b1,
                      const float* __restrict__ g2, const float* __restrict__ b2,
                      const float* __restrict__ spk, float eps2) {
    int row  = blockIdx.x * 4 + (threadIdx.x >> 6);
    int lane = threadIdx.x & 63;
    const float* x = in + (size_t)row * DD;
    float4 a0 = *(const float4*)&x[lane * 4];
    float4 a1 = *(const float4*)&x[256 + lane * 4];
    float v[8] = {a0.x, a0.y, a0.z, a0.w, a1.x, a1.y, a1.z, a1.w};
    float s = 0.f, q = 0.f;
#pragma unroll
    for (int i = 0; i < 8; i++) { s += v[i]; q += v[i] * v[i]; }
#pragma unroll
    for (int m = 1; m < 64; m <<= 1) { s += __shfl_xor(s, m); q += __shfl_xor(q, m); }
    float mean = s * (1.0f / 512.0f);
    float var  = fmaxf(q * (1.0f / 512.0f) - mean * mean, 0.0f);
    float inv  = rsqrtf(var + 1e-5f);
    float4 g0 = *(const float4*)&g1[lane * 4];
    float4 g1v = *(const float4*)&g1[256 + lane * 4];
    float4 b0 = *(const float4*)&b1[lane * 4];
    float4 b1v = *(const float4*)&b1[256 + lane * 4];
    float gv[8] = {g0.x, g0.y, g0.z, g0.w, g1v.x, g1v.y, g1v.z, g1v.w};
    float bv[8] = {b0.x, b0.y, b0.z, b0.w, b1v.x, b1v.y, b1v.z, b1v.w};
    float y[8];
    float s2 = 0.f, q2 = 0.f;
#pragma unroll
    for (int i = 0; i < 8; i++) {
        y[i] = (v[i] - mean) * inv * gv[i] + bv[i];
        s2 += y[i]; q2 += y[i] * y[i];
    }
    if (M2 == 6) {
        float* xo = X + (size_t)row * DD;
        *(float4*)&xo[lane * 4]       = make_float4(y[0], y[1], y[2], y[3]);
        *(float4*)&xo[256 + lane * 4] = make_float4(y[4], y[5], y[6], y[7]);
    }
#pragma unroll
    for (int m = 1; m < 64; m <<= 1) { s2 += __shfl_xor(s2, m); q2 += __shfl_xor(q2, m); }
    float mean2 = s2 * (1.0f / 512.0f);
    float var2  = fmaxf(q2 * (1.0f / 512.0f) - mean2 * mean2, 0.0f);
    float inv2  = rsqrtf(var2 + eps2);
    float4 G0 = *(const float4*)&g2[lane * 4];
    float4 G1 = *(const float4*)&g2[256 + lane * 4];
    float4 B0 = *(const float4*)&b2[lane * 4];
    float4 B1v = *(const float4*)&b2[256 + lane * 4];
    float Gv[8] = {G0.x, G0.y, G0.z, G0.w, G1.x, G1.y, G1.z, G1.w};
    float Bv[8] = {B0.x, B0.y, B0.z, B0.w, B1v.x, B1v.y, B1v.z, B1v.w};
    float z[8];
#pragma unroll
    for (int i = 0; i < 8; i++) z[i] = (y[i] - mean2) * inv2 * Gv[i] + Bv[i];
    if (M2 == 6) {
        uint16_t* o = (uint16_t*)out2 + (size_t)row * DD;
        uint2 p0, p1;
        p0.x = (uint32_t)f2bf(z[0]) | ((uint32_t)f2bf(z[1]) << 16);
        p0.y = (uint32_t)f2bf(z[2]) | ((uint32_t)f2bf(z[3]) << 16);
        p1.x = (uint32_t)f2bf(z[4]) | ((uint32_t)f2bf(z[5]) << 16);
        p1.y = (uint32_t)f2bf(z[6]) | ((uint32_t)f2bf(z[7]) << 16);
        *(uint2*)&o[lane * 4]       = p0;
        *(uint2*)&o[256 + lane * 4] = p1;
    } else {
        const float* sp = spk + (size_t)(row >> 11) * DD;
        float4 s0 = *(const float4*)&sp[lane * 4];
        float4 s1 = *(const float4*)&sp[256 + lane * 4];
        float* o = (float*)out2 + (size_t)row * DD;
        *(float4*)&o[lane * 4]       = make_float4(z[0]+s0.x, z[1]+s0.y, z[2]+s0.z, z[3]+s0.w);
        *(float4*)&o[256 + lane * 4] = make_float4(z[4]+s1.x, z[5]+s1.y, z[6]+s1.z, z[7]+s1.w);
    }
}

// ---------------- fused GLU(+skip into X) + LN -> bf16 ----------------------
__global__ void k_gluln(const uint16_t* __restrict__ H, float* __restrict__ X,
                        uint16_t* __restrict__ out,
                        const float* __restrict__ gam, const float* __restrict__ bet) {
    int row  = blockIdx.x * 4 + (threadIdx.x >> 6);
    int lane = threadIdx.x & 63;
    const uint16_t* hr = H + (size_t)row * 1024;
    uint2 ha0 = *(const uint2*)&hr[lane * 4];
    uint2 ha1 = *(const uint2*)&hr[256 + lane * 4];
    uint2 hg0 = *(const uint2*)&hr[512 + lane * 4];
    uint2 hg1 = *(const uint2*)&hr[768 + lane * 4];
    uint32_t aw[4] = {ha0.x, ha0.y, ha1.x, ha1.y};
    uint32_t gw[4] = {hg0.x, hg0.y, hg1.x, hg1.y};
    float* xr = X + (size_t)row * DD;
    float4 x0 = *(const float4*)&xr[lane * 4];
    float4 x1 = *(const float4*)&xr[256 + lane * 4];
    float xv[8] = {x0.x, x0.y, x0.z, x0.w, x1.x, x1.y, x1.z, x1.w};
    float v[8];
#pragma unroll
    for (int p = 0; p < 4; p++) {
        float a0 = bf2f(aw[p] & 0xffffu), a1 = bf2f(aw[p] >> 16);
        float g0 = bf2f(gw[p] & 0xffffu), g1 = bf2f(gw[p] >> 16);
        v[2*p]   = xv[2*p]   + a0 * sigm(g0);
        v[2*p+1] = xv[2*p+1] + a1 * sigm(g1);
    }
    *(float4*)&xr[lane * 4]       = make_float4(v[0], v[1], v[2], v[3]);
    *(float4*)&xr[256 + lane * 4] = make_float4(v[4], v[5], v[6], v[7]);
    float s = 0.f, q = 0.f;
#pragma unroll
    for (int i = 0; i < 8; i++) { s += v[i]; q += v[i] * v[i]; }
#pragma unroll
    for (int m = 1; m < 64; m <<= 1) { s += __shfl_xor(s, m); q += __shfl_xor(q, m); }
    float mean = s * (1.0f / 512.0f);
    float var  = fmaxf(q * (1.0f / 512.0f) - mean * mean, 0.0f);
    float inv  = rsqrtf(var + 1e-5f);
    float4 g0 = *(const float4*)&gam[lane * 4];
    float4 g1 = *(const float4*)&gam[256 + lane * 4];
    float4 b0 = *(const float4*)&bet[lane * 4];
    float4 b1 = *(const float4*)&bet[256 + lane * 4];
    float gv[8] = {g0.x, g0.y, g0.z, g0.w, g1.x, g1.y, g1.z, g1.w};
    float bv[8] = {b0.x, b0.y, b0.z, b0.w, b1.x, b1.y, b1.z, b1.w};
    uint16_t* o = out + (size_t)row * DD;
    uint2 p0, p1;
    float y0 = (v[0]-mean)*inv*gv[0]+bv[0], y1 = (v[1]-mean)*inv*gv[1]+bv[1];
    float y2 = (v[2]-mean)*inv*gv[2]+bv[2], y3 = (v[3]-mean)*inv*gv[3]+bv[3];
    float y4 = (v[4]-mean)*inv*gv[4]+bv[4], y5 = (v[5]-mean)*inv*gv[5]+bv[5];
    float y6 = (v[6]-mean)*inv*gv[6]+bv[6], y7 = (v[7]-mean)*inv*gv[7]+bv[7];
    p0.x = (uint32_t)f2bf(y0) | ((uint32_t)f2bf(y1) << 16);
    p0.y = (uint32_t)f2bf(y2) | ((uint32_t)f2bf(y3) << 16);
    p1.x = (uint32_t)f2bf(y4) | ((uint32_t)f2bf(y5) << 16);
    p1.y = (uint32_t)f2bf(y6) | ((uint32_t)f2bf(y7) << 16);
    *(uint2*)&o[lane * 4]       = p0;
    *(uint2*)&o[256 + lane * 4] = p1;
}

// ---------------- 256-wide-tile bf16 MFMA GEMM, BK=64, 8 waves, 2-phase -----
// R5-exact structure (proven 84us FFN-a) + fine interleave: stage-A issued
// between k-sub0 reads and MFMAs, stage-B between k-sub1's. One barrier/step.
// MODE 0: gelu->bf16  1: ->bf16  2: X+=0.5v  3: X+=v  4: outf32=X+0.5v
//      5: X=v  6: glu-pairs->bf16 [M][512] (interleaved weights)
template <int MODE, int WM, int WN, int BN>
__global__ __launch_bounds__(512) void k_gemm2(
    const uint16_t* __restrict__ A, const uint16_t* __restrict__ Bt,
    const float* __restrict__ bias, int M, int N, int K,
    void* __restrict__ outp, float* __restrict__ X) {
    constexpr int BM = 256;
    constexpr int MR = BM / WM / 16;
    constexpr int NR = BN / WN / 16;
    constexpr int ABLK = (BM / 16) * 2;          // 32
    constexpr int BBLK = (BN / 16) * 2;          // 32 or 16
    constexpr int APW = ABLK / 8;                // 4
    constexpr int BPW = BBLK / 8;                // 4 or 2
    __shared__ __align__(16) uint16_t As[2][ABLK * 512];
    __shared__ __align__(16) uint16_t Bs[2][BBLK * 512];
    int tid = threadIdx.x;
    int wave = tid >> 6, lane = tid & 63;
    int l15 = lane & 15, l16 = lane >> 4;
    int wr = wave / WN, wc = wave % WN;
    int m0 = blockIdx.x * BM, n0 = blockIdx.y * BN;

    const uint16_t* srcA[APW];
    const uint16_t* srcB[BPW];
#pragma unroll
    for (int p = 0; p < APW; p++) {
        int bi = wave * APW + p, rb = bi >> 1, ks = bi & 1;
        srcA[p] = A + (size_t)(m0 + rb * 16 + l15) * K + ks * 32 + l16 * 8;
    }
#pragma unroll
    for (int p = 0; p < BPW; p++) {
        int bi = wave * BPW + p, rb = bi >> 1, ks = bi & 1;
        srcB[p] = Bt + (size_t)(n0 + rb * 16 + l15) * K + ks * 32 + l16 * 8;
    }

    f32x4 acc[MR][NR];
#pragma unroll
    for (int i = 0; i < MR; i++)
#pragma unroll
        for (int j = 0; j < NR; j++) acc[i][j] = (f32x4){0.f, 0.f, 0.f, 0.f};

    // prologue: stage K-step 0 into buf 0
#pragma unroll
    for (int p = 0; p < APW; p++) gload16(srcA[p], &As[0][(wave * APW + p) * 512]);
#pragma unroll
    for (int p = 0; p < BPW; p++) gload16(srcB[p], &Bs[0][(wave * BPW + p) * 512]);
    __syncthreads();

    int nk = K >> 6;
    for (int it = 0; it < nk; ++it) {
        int cur = it & 1;
        int kt = (it + 1) << 6;
        // ---- k-sub 0 ----
        {
            s16x8 af[MR], bfr[NR];
#pragma unroll
            for (int i = 0; i < MR; i++)
                af[i] = *(const s16x8*)&As[cur][((wr * MR + i) * 2 + 0) * 512 + lane * 8];
#pragma unroll
            for (int j = 0; j < NR; j++)
                bfr[j] = *(const s16x8*)&Bs[cur][((wc * NR + j) * 2 + 0) * 512 + lane * 8];
            if (it + 1 < nk) {
#pragma unroll
                for (int p = 0; p < APW; p++)
                    gload16(srcA[p] + kt, &As[cur ^ 1][(wave * APW + p) * 512]);
            }
#pragma unroll
            for (int i = 0; i < MR; i++)
#pragma unroll
                for (int j = 0; j < NR; j++)
                    acc[i][j] = __builtin_amdgcn_mfma_f32_16x16x32_bf16(af[i], bfr[j], acc[i][j], 0, 0, 0);
        }
        // ---- k-sub 1 ----
        {
            s16x8 af[MR], bfr[NR];
#pragma unroll
            for (int i = 0; i < MR; i++)
                af[i] = *(const s16x8*)&As[cur][((wr * MR + i) * 2 + 1) * 512 + lane * 8];
#pragma unroll
            for (int j = 0; j < NR; j++)
                bfr[j] = *(const s16x8*)&Bs[cur][((wc * NR + j) * 2 + 1) * 512 + lane * 8];
            if (it + 1 < nk) {
#pragma unroll
                for (int p = 0; p < BPW; p++)
                    gload16(srcB[p] + kt, &Bs[cur ^ 1][(wave * BPW + p) * 512]);
            }
#pragma unroll
            for (int i = 0; i < MR; i++)
#pragma unroll
                for (int j = 0; j < NR; j++)
                    acc[i][j] = __builtin_amdgcn_mfma_f32_16x16x32_bf16(af[i], bfr[j], acc[i][j], 0, 0, 0);
        }
        __syncthreads();
    }
    // epilogue: D frag: col=l15, row=l16*4+q
#pragma unroll
    for (int i = 0; i < MR; i++) {
#pragma unroll
        for (int j = 0; j < NR; j++) {
            int gcol = n0 + wc * NR * 16 + j * 16 + l15;
            float bv = bias[gcol];
#pragma unroll
            for (int q = 0; q < 4; q++) {
                int grow = m0 + wr * MR * 16 + i * 16 + l16 * 4 + q;
                float v = acc[i][j][q] + bv;
                if (MODE == 0) {
                    ((uint16_t*)outp)[(size_t)grow * N + gcol] = f2bf(gelu_f(v));
                } else if (MODE == 1) {
                    ((uint16_t*)outp)[(size_t)grow * N + gcol] = f2bf(v);
                } else if (MODE == 2) {
                    X[(size_t)grow * DD + gcol] += 0.5f * v;
                } else if (MODE == 3) {
                    X[(size_t)grow * DD + gcol] += v;
                } else if (MODE == 4) {
                    ((float*)outp)[(size_t)grow * DD + gcol] =
                        X[(size_t)grow * DD + gcol] + 0.5f * v;
                } else if (MODE == 5) {
                    X[(size_t)grow * DD + gcol] = v;
                } else {
                    // MODE 6: interleaved GLU pairs. even col = a, odd = g.
                    float g = __shfl_xor(v, 1);
                    if ((l15 & 1) == 0) {
                        ((uint16_t*)outp)[(size_t)grow * DD + (gcol >> 1)] =
                            f2bf(v * sigm(g));
                    }
                }
            }
        }
    }
}

// ---------------- bf16 transpose [R][C] -> [C][R] per batch z ---------------
__global__ void k_tpose(const uint16_t* __restrict__ in, uint16_t* __restrict__ out,
                        int R, int C) {
    __shared__ uint16_t tile[32][34];
    size_t boff = (size_t)blockIdx.z * R * C;
    int c0 = blockIdx.x * 32, r0 = blockIdx.y * 32;
    int tx = threadIdx.x, ty = threadIdx.y;
#pragma unroll
    for (int i = 0; i < 4; i++)
        tile[ty + i * 8][tx] = in[boff + (size_t)(r0 + ty + i * 8) * C + c0 + tx];
    __syncthreads();
#pragma unroll
    for (int i = 0; i < 4; i++)
        out[boff + (size_t)(c0 + ty + i * 8) * R + r0 + tx] = tile[tx][ty + i * 8];
}

// ===================== DSS chunked-scan machinery ===========================
__global__ __launch_bounds__(64) void k_phiprep(
        const float* __restrict__ lam_re, const float* __restrict__ lam_im,
        const float* __restrict__ log_dt, uint16_t* __restrict__ PHI,
        float* __restrict__ A64f) {
    int l = blockIdx.x, n = threadIdx.x;
    float dt = expf(log_dt[l]);
    float lr = lam_re[l * 64 + n], li = lam_im[l * 64 + n];
    float mag = expf(-expf(lr) * dt), th = li * dt;
    float Are = mag * __cosf(th), Aim = mag * __sinf(th);
    float Pre = 1.f, Pim = 0.f;
    uint16_t* ph = PHI + (size_t)l * 8192;
    for (int tau = 0; tau < 64; tau++) {
        int s = 63 - tau;
        ph[n * 64 + s]        = f2bf(Pre);
        ph[(64 + n) * 64 + s] = f2bf(Pim);
        float nr = Pre * Are - Pim * Aim;
        float ni = Pre * Aim + Pim * Are;
        Pre = nr; Pim = ni;
    }
    A64f[l * 128 + 2 * n]     = Pre;
    A64f[l * 128 + 2 * n + 1] = Pim;
}

__global__ __launch_bounds__(64) void k_gprep(
        const float* __restrict__ lam_re, const float* __restrict__ lam_im,
        const float* __restrict__ c_re, const float* __restrict__ c_im,
        const float* __restrict__ ssm_d, const float* __restrict__ log_dt,
        int l, uint16_t* __restrict__ G) {
    int h = blockIdx.x, n = threadIdx.x;
    __shared__ float klds[64];
    float dt = expf(log_dt[l]);
    float lr = lam_re[l * 64 + n], li = lam_im[l * 64 + n];
    float mag = expf(-expf(lr) * dt), th = li * dt;
    float Are = mag * __cosf(th), Aim = mag * __sinf(th);
    float Cre = c_re[(size_t)l * DD * 64 + h * 64 + n];
    float Cim = c_im[(size_t)l * DD * 64 + h * 64 + n];
    uint16_t* Gh = G + (size_t)h * 64 * 192;
    float Pre = 1.f, Pim = 0.f;
    for (int r = 0; r < 64; r++) {
        float t = Cre * Pre - Cim * Pim;
        float s = t;
        s += __shfl_xor(s, 1);  s += __shfl_xor(s, 2);  s += __shfl_xor(s, 4);
        s += __shfl_xor(s, 8);  s += __shfl_xor(s, 16); s += __shfl_xor(s, 32);
        if (n == 0) klds[r] = dt * s;
        float nr = Pre * Are - Pim * Aim;
        float ni = Pre * Aim + Pim * Are;
        float wre = dt * (Cre * nr - Cim * ni);
        float wim = dt * (Cre * ni + Cim * nr);
        Gh[r * 192 + 64 + n]  = f2bf(wre);
        Gh[r * 192 + 128 + n] = f2bf(-wim);
        Pre = nr; Pim = ni;
    }
    __syncthreads();
    float dh = ssm_d[l * DD + h];
    for (int r = 0; r < 64; r++) {
        int c = n;
        float val = (c < r) ? klds[r - c] : (c == r ? klds[0] + dh : 0.f);
        Gh[r * 192 + c] = f2bf(val);
    }
}

// pass1: E[col][128] = Phi[128x64] @ u-chunks
__global__ __launch_bounds__(256) void k_pass1(
        const uint16_t* __restrict__ u, const uint16_t* __restrict__ PHI,
        uint16_t* __restrict__ E) {
    __shared__ __align__(16) uint16_t Phs[128 * 72];
    int tid = threadIdx.x;
    for (int v = tid; v < 1024; v += 256) {
        int row = v >> 3, kb = v & 7;
        *(s16x8*)&Phs[row * 72 + kb * 8] = *(const s16x8*)&PHI[row * 64 + kb * 8];
    }
    __syncthreads();
    int wave = tid >> 6, lane = tid & 63;
    int l15 = lane & 15, l16 = lane >> 4;
    int m0 = (wave & 1) * 64;
    int colbase = blockIdx.x * 128 + (wave >> 1) * 64;
    f32x4 acc[4][4];
#pragma unroll
    for (int i = 0; i < 4; i++)
#pragma unroll
        for (int j = 0; j < 4; j++) acc[i][j] = (f32x4){0.f, 0.f, 0.f, 0.f};
#pragma unroll
    for (int kt = 0; kt < 64; kt += 32) {
        s16x8 a[4], b[4];
#pragma unroll
        for (int i = 0; i < 4; i++)
            a[i] = *(const s16x8*)&Phs[(m0 + i * 16 + l15) * 72 + kt + l16 * 8];
#pragma unroll
        for (int j = 0; j < 4; j++)
            b[j] = *(const s16x8*)(u + (size_t)(colbase + j * 16 + l15) * 64 + kt + l16 * 8);
#pragma unroll
        for (int i = 0; i < 4; i++)
#pragma unroll
            for (int j = 0; j < 4; j++)
                acc[i][j] = __builtin_amdgcn_mfma_f32_16x16x32_bf16(a[i], b[j], acc[i][j], 0, 0, 0);
    }
#pragma unroll
    for (int i = 0; i < 4; i++)
#pragma unroll
        for (int j = 0; j < 4; j++) {
            int col = colbase + j * 16 + l15;
            int r0  = m0 + i * 16 + l16 * 4;
            uint32_t p0 = (uint32_t)f2bf(acc[i][j][0]) | ((uint32_t)f2bf(acc[i][j][1]) << 16);
            uint32_t p1 = (uint32_t)f2bf(acc[i][j][2]) | ((uint32_t)f2bf(acc[i][j][3]) << 16);
            *(uint2*)&E[(size_t)col * 128 + r0] = make_uint2(p0, p1);
        }
}

// pass2: chunk-boundary states
__global__ void k_pass2(const uint16_t* __restrict__ E, const float* __restrict__ A64f,
                        int l, uint16_t* __restrict__ Sp) {
    int gid = blockIdx.x * 256 + threadIdx.x;
    int n = gid & 63, bh = gid >> 6;
    int b = bh >> 9, h = bh & 511;
    float2 A = *(const float2*)&A64f[l * 128 + 2 * n];
    float Sre = 0.f, Sim = 0.f;
    const uint16_t* Eb = E + (size_t)bh * 32 * 128;
    uint16_t* So = Sp + (size_t)h * 32768 + (size_t)b * 32 * 128;
    for (int i = 0; i < 32; i++) {
        So[i * 128 + n]      = f2bf(Sre);
        So[i * 128 + 64 + n] = f2bf(Sim);
        float er = bf2f((uint32_t)Eb[i * 128 + n]);
        float ei = bf2f((uint32_t)Eb[i * 128 + 64 + n]);
        float nr = A.x * Sre - A.y * Sim + er;
        float ni = A.x * Sim + A.y * Sre + ei;
        Sre = nr; Sim = ni;
    }
}

// pass3: per-h GEMM  Y[64 x 256cols] = G_h[64x192] @ [u;Sre;Sim]
__global__ __launch_bounds__(256) void k_pass3(
        const uint16_t* __restrict__ G, const uint16_t* __restrict__ u,
        const uint16_t* __restrict__ Sp, uint16_t* __restrict__ Y) {
    __shared__ __align__(16) uint16_t Gs[64 * 200];
    int h = blockIdx.x, tid = threadIdx.x;
    for (int v = tid; v < 1536; v += 256) {
        int row = v / 24, kb = v % 24;
        *(s16x8*)&Gs[row * 200 + kb * 8] = *(const s16x8*)&G[(size_t)h * 12288 + row * 192 + kb * 8];
    }
    __syncthreads();
    int wave = tid >> 6, lane = tid & 63;
    int l15 = lane & 15, l16 = lane >> 4;
    int wn = wave * 64;
    const uint16_t* uh = u + (size_t)h * TT;
    const uint16_t* sh = Sp + (size_t)h * 32768;
    f32x4 acc[4][4];
#pragma unroll
    for (int i = 0; i < 4; i++)
#pragma unroll
        for (int j = 0; j < 4; j++) acc[i][j] = (f32x4){0.f, 0.f, 0.f, 0.f};
#pragma unroll
    for (int kt = 0; kt < 192; kt += 32) {
        s16x8 a[4], b[4];
#pragma unroll
        for (int i = 0; i < 4; i++)
            a[i] = *(const s16x8*)&Gs[(i * 16 + l15) * 200 + kt + l16 * 8];
#pragma unroll
        for (int j = 0; j < 4; j++) {
            int col = wn + j * 16 + l15;
            const uint16_t* src;
            if (kt < 64)
                src = uh + (size_t)(col >> 5) * (DD * TT) + (col & 31) * 64 + kt + l16 * 8;
            else
                src = sh + (size_t)col * 128 + (kt - 64) + l16 * 8;
            b[j] = *(const s16x8*)src;
        }
#pragma unroll
        for (int i = 0; i < 4; i++)
#pragma unroll
            for (int j = 0; j < 4; j++)
                acc[i][j] = __builtin_amdgcn_mfma_f32_16x16x32_bf16(a[i], b[j], acc[i][j], 0, 0, 0);
    }
#pragma unroll
    for (int i = 0; i < 4; i++)
#pragma unroll
        for (int j = 0; j < 4; j++) {
            int col = wn + j * 16 + l15;
            int r0  = i * 16 + l16 * 4;
            uint16_t* dst = Y + (size_t)(col >> 5) * (DD * TT) + (size_t)h * TT + (col & 31) * 64 + r0;
            uint32_t p0 = (uint32_t)f2bf(acc[i][j][0]) | ((uint32_t)f2bf(acc[i][j][1]) << 16);
            uint32_t p1 = (uint32_t)f2bf(acc[i][j][2]) | ((uint32_t)f2bf(acc[i][j][3]) << 16);
            *(uint2*)&dst[0] = make_uint2(p0, p1);
        }
}

// ---------------- gelu + transpose [b][h][t] -> [b][t][h] -------------------
__global__ void k_tgelu(const uint16_t* __restrict__ y, uint16_t* __restrict__ out) {
    __shared__ uint16_t tile[32][34];
    int b = blockIdx.z;
    int t0 = blockIdx.x * 32, h0 = blockIdx.y * 32;
    int tx = threadIdx.x, ty = threadIdx.y;
    const uint16_t* yb = y + (size_t)b * DD * TT;
#pragma unroll
    for (int i = 0; i < 4; i++) {
        int h = h0 + ty + i * 8;
        tile[ty + i * 8][tx] = f2bf(gelu_f(bf2f((uint32_t)yb[(size_t)h * TT + t0 + tx])));
    }
    __syncthreads();
    uint16_t* ob = out + (size_t)b * TT * DD;
#pragma unroll
    for (int i = 0; i < 4; i++) {
        int t = t0 + ty + i * 8;
        ob[(size_t)t * DD + h0 + tx] = tile[tx][ty + i * 8];
    }
}

// ---------------- fused depthwise conv k=31 + LN + gelu, 16 rows/block ------
__global__ __launch_bounds__(256) void k_dwln(
        const uint16_t* __restrict__ in, const float* __restrict__ dwt,
        const float* __restrict__ db, const float* __restrict__ gam,
        const float* __restrict__ bet, uint16_t* __restrict__ out) {
    __shared__ __align__(16) uint16_t xs[46 * 512];
    __shared__ float red[16][4][2];
    int tid = threadIdx.x;
    int t0 = (blockIdx.x & 127) * 16;
    int b  = blockIdx.x >> 7;
    const uint16_t* ib = in + (size_t)b * TT * DD;
    for (int v = tid; v < 46 * 64; v += 256) {
        int row = v >> 6, seg = v & 63;
        int tj = t0 - 15 + row;
        uint4 val = make_uint4(0, 0, 0, 0);
        if (tj >= 0 && tj < TT) val = *(const uint4*)&ib[(size_t)tj * DD + seg * 8];
        *(uint4*)&xs[row * 512 + seg * 8] = val;
    }
    __syncthreads();
    int d = tid * 2;
    int wave = tid >> 6, lane = tid & 63;
    float a0[16], a1[16];
    float bv0 = db[d], bv1 = db[d + 1];
#pragma unroll
    for (int o = 0; o < 16; o++) { a0[o] = bv0; a1[o] = bv1; }
#pragma unroll
    for (int k = 0; k < 31; k++) {
        float2 w = *(const float2*)&dwt[k * DD + d];
#pragma unroll
        for (int o = 0; o < 16; o++) {
            uint32_t v = *(const uint32_t*)&xs[(o + k) * 512 + d];
            a0[o] = fmaf(bf2f(v & 0xffffu), w.x, a0[o]);
            a1[o] = fmaf(bf2f(v >> 16), w.y, a1[o]);
        }
    }
#pragma unroll
    for (int o = 0; o < 16; o++) {
        float ss = a0[o] + a1[o];
        float qq = a0[o] * a0[o] + a1[o] * a1[o];
#pragma unroll
        for (int m = 1; m < 64; m <<= 1) { ss += __shfl_xor(ss, m); qq += __shfl_xor(qq, m); }
        if (lane == 0) { red[o][wave][0] = ss; red[o][wave][1] = qq; }
    }
    __syncthreads();
    float g0 = gam[d], g1 = gam[d + 1], be0 = bet[d], be1 = bet[d + 1];
#pragma unroll
    for (int o = 0; o < 16; o++) {
        float s = red[o][0][0] + red[o][1][0] + red[o][2][0] + red[o][3][0];
        float q = red[o][0][1] + red[o][1][1] + red[o][2][1] + red[o][3][1];
        float mean = s * (1.0f / 512.0f);
        float var  = fmaxf(q * (1.0f / 512.0f) - mean * mean, 0.0f);
        float inv  = rsqrtf(var + 1e-5f);
        float y0 = gelu_f((a0[o] - mean) * inv * g0 + be0);
        float y1 = gelu_f((a1[o] - mean) * inv * g1 + be1);
        uint32_t p = (uint32_t)f2bf(y0) | ((uint32_t)f2bf(y1) << 16);
        *(uint32_t*)&out[((size_t)b * TT + t0 + o) * DD + d] = p;
    }
}

// ---------------------------------------------------------------------------
extern "C" void kernel_launch(void* const* d_in, const int* in_sizes, int n_in,
                              void* d_out, int out_size, void* d_ws, size_t ws_size,
                              hipStream_t stream) {
    const float* src        = (const float*)d_in[0];
    const float* speaker    = (const float*)d_in[1];
    const float* src_w      = (const float*)d_in[2];
    const float* src_b      = (const float*)d_in[3];
    const float* ffn1_ln_g  = (const float*)d_in[4];
    const float* ffn1_ln_b  = (const float*)d_in[5];
    const float* ffn1_w1    = (const float*)d_in[6];
    const float* ffn1_b1    = (const float*)d_in[7];
    const float* ffn1_w2    = (const float*)d_in[8];
    const float* ffn1_b2    = (const float*)d_in[9];
    const float* norm1_g    = (const float*)d_in[10];
    const float* norm1_b    = (const float*)d_in[11];
    const float* lam_re     = (const float*)d_in[12];
    const float* lam_im     = (const float*)d_in[13];
    const float* c_re       = (const float*)d_in[14];
    const float* c_im       = (const float*)d_in[15];
    const float* ssm_d      = (const float*)d_in[16];
    const float* log_dt     = (const float*)d_in[17];
    const float* dss_out_w  = (const float*)d_in[18];
    const float* dss_out_b  = (const float*)d_in[19];
    const float* conv_ln_g  = (const float*)d_in[20];
    const float* conv_ln_b  = (const float*)d_in[21];
    const float* bneck_w    = (const float*)d_in[22];
    const float* bneck_b    = (const float*)d_in[23];
    const float* dw_w       = (const float*)d_in[24];
    const float* dw_b       = (const float*)d_in[25];
    const float* conv_ln2_g = (const float*)d_in[26];
    const float* conv_ln2_b = (const float*)d_in[27];
    const float* conv_lin_w = (const float*)d_in[28];
    const float* conv_lin_b = (const float*)d_in[29];
    const float* ffn2_ln_g  = (const float*)d_in[30];
    const float* ffn2_ln_b  = (const float*)d_in[31];
    const float* ffn2_w1    = (const float*)d_in[32];
    const float* ffn2_b1    = (const float*)d_in[33];
    const float* ffn2_w2    = (const float*)d_in[34];
    const float* ffn2_b2    = (const float*)d_in[35];
    const float* norm2_g    = (const float*)d_in[36];
    const float* norm2_b    = (const float*)d_in[37];
    const float* final_g    = (const float*)d_in[38];
    const float* final_b    = (const float*)d_in[39];
    (void)in_sizes; (void)n_in; (void)out_size; (void)ws_size;

    uint8_t* ws = (uint8_t*)d_ws;
    float*    X   = (float*)   (ws + 0);                     // f32 [16384][512]
    float*    F0  = (float*)   (ws + 33554432);              // f32 [16384][512] / Spack
    uint16_t* B1  = (uint16_t*)(ws + 67108864);              // bf16 [16384][512] / G
    uint16_t* B2  = (uint16_t*)(ws + 83886080);              // bf16 u / Wsrc
    uint16_t* B3  = (uint16_t*)(ws + 100663296);             // bf16 y / src_bf16
    uint16_t* H   = (uint16_t*)(ws + 117440512);             // bf16 GEMM mids / E
    uint16_t* Wf1a= (uint16_t*)(ws + 184549376);
    uint16_t* Wf1b= (uint16_t*)(ws + 197132288);
    uint16_t* Wds = (uint16_t*)(ws + 209715200);
    uint16_t* Wbn = (uint16_t*)(ws + 216006656);             // interleaved GLU weights
    uint16_t* Wcl = (uint16_t*)(ws + 222298112);
    uint16_t* Wf2a= (uint16_t*)(ws + 225443840);
    uint16_t* Wf2b= (uint16_t*)(ws + 238026752);
    float*    DWT = (float*)   (ws + 250609664);
    uint16_t* PHI = (uint16_t*)(ws + 250990592);
    float*    A64f= (float*)   (ws + 251088896);
    float*    BNB = (float*)   (ws + 251092992);             // interleaved bneck bias

    uint16_t* GBUF = B1;
    uint16_t* SPK  = (uint16_t*)F0;
    uint16_t* EBUF = H;
    uint16_t* SRCB = B3;                                     // src bf16 [16384][128]
    uint16_t* WSRC = B2;                                     // src_w bf16 [512][128]

    dim3 tb(32, 8);
    k_wtrans<<<dim3(FF/32, DD/32, NL), tb, 0, stream>>>(ffn1_w1, Wf1a, DD, FF);
    k_wtrans<<<dim3(DD/32, FF/32, NL), tb, 0, stream>>>(ffn1_w2, Wf1b, FF, DD);
    k_wtrans<<<dim3(1024/32, DD/32, NL), tb, 0, stream>>>(dss_out_w, Wds, DD, 1024);
    k_wglu<<<(NL*1024*DD + 255)/256, 256, 0, stream>>>(bneck_w, bneck_b, Wbn, BNB);
    k_wcvt<<<(NL*DD*DD + 255)/256, 256, 0, stream>>>(conv_lin_w, Wcl, NL*DD*DD);
    k_wtrans<<<dim3(FF/32, DD/32, NL), tb, 0, stream>>>(ffn2_w1, Wf2a, DD, FF);
    k_wtrans<<<dim3(DD/32, FF/32, NL), tb, 0, stream>>>(ffn2_w2, Wf2b, FF, DD);
    k_dwt<<<(NL*DD*31 + 255)/256, 256, 0, stream>>>(dw_w, DWT);
    k_phiprep<<<NL, 64, 0, stream>>>(lam_re, lam_im, log_dt, PHI, A64f);
    k_srcpad<<<(ROWS*128 + 255)/256, 256, 0, stream>>>(src, SRCB);
    k_wsrcpad<<<(DD*128 + 255)/256, 256, 0, stream>>>(src_w, WSRC);

    // input projection: X = src @ W + b  (K padded to 128)
    k_gemm2<5,4,2,128><<<dim3(64, 4), 512, 0, stream>>>(SRCB, WSRC, src_b, ROWS, DD, 128, nullptr, X);
    // first ffn1 LN
    k_ln<0><<<4096, 256, 0, stream>>>(X, B1, ffn1_ln_g, ffn1_ln_b, nullptr, 1e-5f);

    for (int l = 0; l < NL; l++) {
        // 1. FFN1 (B1 = LN(x) precomputed)
        k_gemm2<0,2,4,256><<<dim3(64, 8), 512, 0, stream>>>(B1, Wf1a + (size_t)l*FF*DD, ffn1_b1 + l*FF,
                                                            ROWS, FF, DD, H, nullptr);
        k_gemm2<2,4,2,128><<<dim3(64, 4), 512, 0, stream>>>(H, Wf1b + (size_t)l*DD*FF, ffn1_b2 + l*DD,
                                                            ROWS, DD, FF, nullptr, X);
        // 2. DSS
        k_ln<0><<<4096, 256, 0, stream>>>(X, B1, norm1_g + l*DD, norm1_b + l*DD, nullptr, 1e-5f);
        k_tpose<<<dim3(DD/32, TT/32, BB), tb, 0, stream>>>(B1, B2, TT, DD);
        k_gprep<<<DD, 64, 0, stream>>>(lam_re, lam_im, c_re, c_im, ssm_d, log_dt, l, GBUF);
        k_pass1<<<1024, 256, 0, stream>>>(B2, PHI + (size_t)l*8192, EBUF);
        k_pass2<<<1024, 256, 0, stream>>>(EBUF, A64f, l, SPK);
        k_pass3<<<DD, 256, 0, stream>>>(GBUF, B2, SPK, B3);
        k_tgelu<<<dim3(TT/32, DD/32, BB), tb, 0, stream>>>(B3, B1);
        k_gemm2<1,2,4,256><<<dim3(64, 4), 512, 0, stream>>>(B1, Wds + (size_t)l*1024*DD, dss_out_b + l*1024,
                                                            ROWS, 1024, DD, H, nullptr);
        // fused GLU(+skip) + conv LN
        k_gluln<<<4096, 256, 0, stream>>>(H, X, B1, conv_ln_g + l*DD, conv_ln_b + l*DD);
        // 3. Conv module (GLU fused into bneck GEMM epilogue via MODE 6)
        k_gemm2<6,2,4,256><<<dim3(64, 4), 512, 0, stream>>>(B1, Wbn + (size_t)l*1024*DD, BNB + l*1024,
                                                            ROWS, 1024, DD, B2, nullptr);
        k_dwln<<<BB*128, 256, 0, stream>>>(B2, DWT + (size_t)l*31*DD, dw_b + l*DD,
                                           conv_ln2_g + l*DD, conv_ln2_b + l*DD, B1);
        k_gemm2<3,4,2,128><<<dim3(64, 4), 512, 0, stream>>>(B1, Wcl + (size_t)l*DD*DD, conv_lin_b + l*DD,
                                                            ROWS, DD, DD, nullptr, X);
        // 4. FFN2
        k_ln<0><<<4096, 256, 0, stream>>>(X, B1, ffn2_ln_g + l*DD, ffn2_ln_b + l*DD, nullptr, 1e-5f);
        k_gemm2<0,2,4,256><<<dim3(64, 8), 512, 0, stream>>>(B1, Wf2a + (size_t)l*FF*DD, ffn2_b1 + l*FF,
                                                            ROWS, FF, DD, H, nullptr);
        k_gemm2<4,4,2,128><<<dim3(64, 4), 512, 0, stream>>>(H, Wf2b + (size_t)l*DD*FF, ffn2_b2 + l*DD,
                                                            ROWS, DD, FF, F0, X);
        // norm2 (+ next-layer ffn1 LN, or final LN + speaker)
        if (l < NL - 1) {
            k_ln2<6><<<4096, 256, 0, stream>>>(F0, X, B1, norm2_g + l*DD, norm2_b + l*DD,
                                               ffn1_ln_g + (l+1)*DD, ffn1_ln_b + (l+1)*DD,
                                               nullptr, 1e-5f);
        } else {
            k_ln2<7><<<4096, 256, 0, stream>>>(F0, nullptr, d_out, norm2_g + l*DD, norm2_b + l*DD,
                                               final_g, final_b, speaker, 1e-6f);
        }
    }
}